// Round 7
// baseline (839.253 us; speedup 1.0000x reference)
//
#include <hip/hip_runtime.h>
#include <math.h>

#define S_LEN 8192
#define B_N   16
#define NBC   1024          // B*C rows
#define L1v 4103
#define L2v 2059
#define L3v 1037
#define L4v 526
#define LP1 4104
#define LP2 2060
#define LP3 1040
#define LP4 528

// bf16 weight buffer offsets (ushorts)
#define OFF_CONV 0          // 4 x 12288  [o][tap*64+c]
#define OFF_M1   49152      // 4 x 8192   [m][k]
#define OFF_M2   81920      // 4 x 8192
#define OFF_CD   114688     // 4 x 16384  [lvl][o][c]
#define OFF_CA   180224     // 4 x 4096
#define OFF_P1   196608     // 2048
#define OFF_P2   198656     // 2048
#define WTOT     200704

typedef __attribute__((ext_vector_type(8))) short bf16x8;
typedef __attribute__((ext_vector_type(4))) float f32x4;

__constant__ float c_dlo[16] = {
    -0.0033824159510061256f, -0.0005421323317911481f,  0.03169508781149298f,
     0.007607487324917605f,  -0.1432942383508097f,    -0.061273359067658524f,
     0.4813596512583722f,     0.7771857517005235f,     0.3644418948353314f,
    -0.05194583810770904f,   -0.027219029917056003f,   0.049137179673607506f,
     0.003808752013890615f,  -0.01495225833704823f,   -0.0003029205147213668f,
     0.0018899503327594609f
};
__constant__ float c_dhi[16] = {
    -0.0018899503327594609f, -0.0003029205147213668f,  0.01495225833704823f,
     0.003808752013890615f,  -0.049137179673607506f,  -0.027219029917056003f,
     0.05194583810770904f,    0.3644418948353314f,    -0.7771857517005235f,
     0.4813596512583722f,     0.061273359067658524f,  -0.1432942383508097f,
    -0.007607487324917605f,   0.03169508781149298f,    0.0005421323317911481f,
    -0.0033824159510061256f
};

__device__ __forceinline__ float gelu1(float x) {
    return 0.5f * x * (1.0f + erff(x * 0.70710678118654752f));
}
__device__ __forceinline__ float4 load4g(const float* __restrict__ row, int l, int L) {
    float4 v;
    if (l >= 0 && l + 3 < L) {
        v = *(const float4*)(row + l);
    } else {
        v.x = (l     >= 0 && l     < L) ? row[l]     : 0.f;
        v.y = (l + 1 >= 0 && l + 1 < L) ? row[l + 1] : 0.f;
        v.z = (l + 2 >= 0 && l + 2 < L) ? row[l + 2] : 0.f;
        v.w = (l + 3 >= 0 && l + 3 < L) ? row[l + 3] : 0.f;
    }
    return v;
}
__device__ __forceinline__ void store4g(float* __restrict__ row, int l, int L, float4 v) {
    if (l + 3 < L) {
        *(float4*)(row + l) = v;
    } else {
        if (l     < L) row[l]     = v.x;
        if (l + 1 < L) row[l + 1] = v.y;
        if (l + 2 < L) row[l + 2] = v.z;
        if (l + 3 < L) row[l + 3] = v.w;
    }
}
__device__ __forceinline__ ushort f2bf(float f) {
    uint u = __float_as_uint(f);
    u += 0x7fffu + ((u >> 16) & 1u);
    return (ushort)(u >> 16);
}
__device__ __forceinline__ uint pack2bf(float a, float b) {
    return (uint)f2bf(a) | ((uint)f2bf(b) << 16);
}

// ---------------- one-time weight prep: f32 -> bf16 (conv reordered) ----------------
__global__ __launch_bounds__(256) void prep_kernel(const float* __restrict__ convW,
                                                   const float* __restrict__ m1,
                                                   const float* __restrict__ m2,
                                                   const float* __restrict__ cd,
                                                   const float* __restrict__ ca,
                                                   const float* __restrict__ p1,
                                                   const float* __restrict__ p2,
                                                   ushort* __restrict__ wbuf) {
    int idx = blockIdx.x * 256 + threadIdx.x;
    if (idx >= WTOT) return;
    float v;
    if (idx < OFF_M1) {
        int i = idx / 12288, r = idx % 12288;
        int o = r / 192, k = r % 192;
        int tap = k >> 6, c = k & 63;
        v = convW[i * 12288 + o * 192 + c * 3 + tap];
    } else if (idx < OFF_M2) v = m1[idx - OFF_M1];
    else if (idx < OFF_CD)   v = m2[idx - OFF_M2];
    else if (idx < OFF_CA)   v = cd[idx - OFF_CD];
    else if (idx < OFF_P1)   v = ca[idx - OFF_CA];
    else if (idx < OFF_P2)   v = p1[idx - OFF_P1];
    else                     v = p2[idx - OFF_P2];
    wbuf[idx] = f2bf(v);
}

// ---------------- lift ----------------
__global__ __launch_bounds__(256) void lift_kernel(const float* __restrict__ x,
                                                   const float* __restrict__ w,
                                                   const float* __restrict__ bias,
                                                   float* __restrict__ out) {
    int idx = blockIdx.x * 256 + threadIdx.x;
    int s = idx & (S_LEN - 1);
    int r = idx >> 13;
    int o = r & 63;
    int b = r >> 6;
    float g = -1.0f + 2.0f * (float)s / (float)(S_LEN - 1);
    out[idx] = fmaf(w[o * 2 + 0], x[b * S_LEN + s], fmaf(w[o * 2 + 1], g, bias[o]));
}

// ---------------- row stats: mean + rsqrt(var+eps) ----------------
__global__ __launch_bounds__(256) void stats_kernel(const float* __restrict__ in,
                                                    float2* __restrict__ stats) {
    const int base = blockIdx.x * S_LEN;
    const int tid = threadIdx.x;
    float s = 0.f, ss = 0.f;
#pragma unroll
    for (int i = 0; i < 8; ++i) {
        float4 v = *(const float4*)(in + base + (tid + i * 256) * 4);
        s += v.x + v.y + v.z + v.w;
        ss = fmaf(v.x, v.x, fmaf(v.y, v.y, fmaf(v.z, v.z, fmaf(v.w, v.w, ss))));
    }
    for (int off = 32; off > 0; off >>= 1) {
        s  += __shfl_down(s, off, 64);
        ss += __shfl_down(ss, off, 64);
    }
    __shared__ float sh[8];
    int lane = tid & 63, wv = tid >> 6;
    if (lane == 0) { sh[wv] = s; sh[4 + wv] = ss; }
    __syncthreads();
    if (tid == 0) {
        float tot  = sh[0] + sh[1] + sh[2] + sh[3];
        float tot2 = sh[4] + sh[5] + sh[6] + sh[7];
        float mean = tot * (1.0f / S_LEN);
        float var  = tot2 * (1.0f / S_LEN) - mean * mean;
        stats[blockIdx.x] = make_float2(mean, rsqrtf(var + 1e-5f));
    }
}

// ---------------- conv1d k=3 via bf16 MFMA; input normalized on the fly -------------
#define CWP 200
#define CXP 72

__global__ __launch_bounds__(256) void conv3_mfma_kernel(const float* __restrict__ in,
                                                         float* __restrict__ out,
                                                         const ushort* __restrict__ Wbf,   // [o][tap*64+c] bf16
                                                         const float* __restrict__ bias,
                                                         const float2* __restrict__ stats) {
    __shared__ ushort sW[64 * CWP];
    __shared__ ushort sXt[144 * CXP];
    const int b = blockIdx.y;
    const int n0 = blockIdx.x * 128;
    const int tid = threadIdx.x;

    {   // stage pre-converted W: plain 16B copies
        const int o = tid >> 2, q = tid & 3;
        const uint4* src = (const uint4*)(Wbf + o * 192 + q * 48);
        uint4* dst = (uint4*)(sW + o * CWP + q * 48);
#pragma unroll
        for (int i = 0; i < 6; ++i) dst[i] = src[i];
    }
    {   // stage x^T normalized (zero outside [0,S_LEN))
        const int ch = tid >> 2, q = tid & 3;
        const int rowi = b * 64 + ch;
        const float2 st = stats[rowi];
        const float* row = in + (size_t)rowi * S_LEN;
#pragma unroll
        for (int i = 0; i < 9; ++i) {
            int p = q * 36 + i * 4;
            int l = n0 - 8 + p;
            float4 v;
            if (l >= 0 && l + 3 < S_LEN) {
                v = *(const float4*)(row + l);
                v.x = (v.x - st.x) * st.y; v.y = (v.y - st.x) * st.y;
                v.z = (v.z - st.x) * st.y; v.w = (v.w - st.x) * st.y;
            } else {
                v.x = (l     >= 0 && l     < S_LEN) ? (row[l]     - st.x) * st.y : 0.f;
                v.y = (l + 1 >= 0 && l + 1 < S_LEN) ? (row[l + 1] - st.x) * st.y : 0.f;
                v.z = (l + 2 >= 0 && l + 2 < S_LEN) ? (row[l + 2] - st.x) * st.y : 0.f;
                v.w = (l + 3 >= 0 && l + 3 < S_LEN) ? (row[l + 3] - st.x) * st.y : 0.f;
            }
            sXt[(p + 0) * CXP + ch] = f2bf(v.x);
            sXt[(p + 1) * CXP + ch] = f2bf(v.y);
            sXt[(p + 2) * CXP + ch] = f2bf(v.z);
            sXt[(p + 3) * CXP + ch] = f2bf(v.w);
        }
    }
    __syncthreads();

    const int w = tid >> 6, l = tid & 63, g = l >> 4, c = l & 15;
    f32x4 acc[2][4];
#pragma unroll
    for (int mt = 0; mt < 4; ++mt) {
        float4 bv = *(const float4*)(bias + 16 * mt + 4 * g);
#pragma unroll
        for (int t = 0; t < 2; ++t) {
            acc[t][mt][0] = bv.x; acc[t][mt][1] = bv.y;
            acc[t][mt][2] = bv.z; acc[t][mt][3] = bv.w;
        }
    }
#pragma unroll
    for (int kk = 0; kk < 6; ++kk) {
        const int tap = kk >> 1;
        bf16x8 af[4];
#pragma unroll
        for (int mt = 0; mt < 4; ++mt)
            af[mt] = *(bf16x8*)(sW + (16 * mt + c) * CWP + kk * 32 + 8 * g);
#pragma unroll
        for (int t = 0; t < 2; ++t) {
            const int nl = 32 * w + 16 * t + c;
            const int p = nl + tap + 7;
            bf16x8 xb = *(bf16x8*)(sXt + p * CXP + (kk & 1) * 32 + 8 * g);
#pragma unroll
            for (int mt = 0; mt < 4; ++mt)
                acc[t][mt] = __builtin_amdgcn_mfma_f32_16x16x32_bf16(af[mt], xb, acc[t][mt], 0, 0, 0);
        }
    }
#pragma unroll
    for (int t = 0; t < 2; ++t) {
        const int nl = 32 * w + 16 * t + c;
#pragma unroll
        for (int mt = 0; mt < 4; ++mt)
#pragma unroll
            for (int r = 0; r < 4; ++r) {
                int m = 16 * mt + 4 * g + r;
                out[((size_t)(b * 64 + m)) * S_LEN + n0 + nl] = acc[t][mt][r];
            }
    }
}

// ---------------- consolidated wavelet-domain channel mix (bf16 MFMA, in-place) --------
#define WMP 72
#define WXP 136

__global__ __launch_bounds__(256) void wmix_kernel(float* __restrict__ d1,
                                                   float* __restrict__ d2,
                                                   float* __restrict__ d3,
                                                   float* __restrict__ d4,
                                                   float* __restrict__ a4,
                                                   const ushort* __restrict__ cdbf,
                                                   const float* __restrict__ cd_b,
                                                   const ushort* __restrict__ cabf,
                                                   const float* __restrict__ ca_b) {
    __shared__ ushort sW[64 * WMP];
    __shared__ ushort sX[64 * WXP];
    const int b = blockIdx.y;
    const int t = blockIdx.x;
    float* buf; const ushort* W; const float* bias; int L, LP, l0;
    if (t < 33)      { buf = d1; W = cdbf + 3 * 4096; bias = cd_b + 3 * 64; L = L1v; LP = LP1; l0 = t * 128; }
    else if (t < 50) { buf = d2; W = cdbf + 2 * 4096; bias = cd_b + 2 * 64; L = L2v; LP = LP2; l0 = (t - 33) * 128; }
    else if (t < 59) { buf = d3; W = cdbf + 1 * 4096; bias = cd_b + 1 * 64; L = L3v; LP = LP3; l0 = (t - 50) * 128; }
    else if (t < 64) { buf = d4; W = cdbf;            bias = cd_b;          L = L4v; LP = LP4; l0 = (t - 59) * 128; }
    else             { buf = a4; W = cabf;            bias = ca_b;          L = L4v; LP = LP4; l0 = (t - 64) * 128; }
    const int tid = threadIdx.x;
    {   // stage W (64x64 bf16): plain copies
        int row = tid >> 2, q = tid & 3;
        const uint4* src = (const uint4*)(W + row * 64 + q * 16);
        uint4* dst = (uint4*)(sW + row * WMP + q * 16);
        dst[0] = src[0]; dst[1] = src[1];
    }
    {   // stage x tile [ch][128 pos]
        int ch = tid >> 2, part = tid & 3;
        const float* src = buf + ((size_t)(b * 64 + ch)) * LP;
        uint* dst = (uint*)(sX + ch * WXP + part * 32);
#pragma unroll
        for (int i = 0; i < 8; ++i) {
            int l = l0 + part * 32 + 4 * i;
            float4 v = load4g(src, l, L);
            dst[2 * i]     = pack2bf(v.x, v.y);
            dst[2 * i + 1] = pack2bf(v.z, v.w);
        }
    }
    __syncthreads();
    const int w = tid >> 6, l = tid & 63, g = l >> 4, c = l & 15;
    f32x4 acc[2][4];
#pragma unroll
    for (int mt = 0; mt < 4; ++mt) {
        float4 bv = *(const float4*)(bias + 16 * mt + 4 * g);
#pragma unroll
        for (int tt = 0; tt < 2; ++tt) {
            acc[tt][mt][0] = bv.x; acc[tt][mt][1] = bv.y;
            acc[tt][mt][2] = bv.z; acc[tt][mt][3] = bv.w;
        }
    }
#pragma unroll
    for (int kk = 0; kk < 2; ++kk) {
        bf16x8 af[4];
#pragma unroll
        for (int mt = 0; mt < 4; ++mt)
            af[mt] = *(bf16x8*)(sW + (16 * mt + c) * WMP + kk * 32 + 8 * g);
#pragma unroll
        for (int tt = 0; tt < 2; ++tt) {
            const int nl = 32 * w + 16 * tt + c;
            bf16x8 xb;
#pragma unroll
            for (int j = 0; j < 8; ++j)
                xb[j] = (short)sX[(kk * 32 + 8 * g + j) * WXP + nl];
#pragma unroll
            for (int mt = 0; mt < 4; ++mt)
                acc[tt][mt] = __builtin_amdgcn_mfma_f32_16x16x32_bf16(af[mt], xb, acc[tt][mt], 0, 0, 0);
        }
    }
#pragma unroll
    for (int tt = 0; tt < 2; ++tt) {
        const int nl = 32 * w + 16 * tt + c;
        if (l0 + nl < L) {
#pragma unroll
            for (int mt = 0; mt < 4; ++mt)
#pragma unroll
                for (int r = 0; r < 4; ++r) {
                    int m = 16 * mt + 4 * g + r;
                    buf[((size_t)(b * 64 + m)) * LP + l0 + nl] = acc[tt][mt][r];
                }
        }
    }
}

// ---------------- fused MLP v2: 128-pos tile, weights direct from global bf16 ----------
#define XP2 132
#define MP2 136

__global__ __launch_bounds__(256) void mlp_kernel(float* __restrict__ A,
                                                  const float2* __restrict__ stats,
                                                  const ushort* __restrict__ W1bf,  // [128][64]
                                                  const float* __restrict__ b1,
                                                  const ushort* __restrict__ W2bf,  // [64][128]
                                                  const float* __restrict__ b2) {
    __shared__ ushort sX [64 * XP2];    // [ch][pos]  16.9 KB
    __shared__ ushort sMid[128 * MP2];  // [pos][mid] 34.8 KB
    const int b  = blockIdx.y;
    const int n0 = blockIdx.x * 128;
    const int tid = threadIdx.x;

    {   // stage xn tile: normalize A[ch][n0..n0+127] -> bf16 [ch][pos]
        int ch = tid >> 2, part = tid & 3;
        float2 st = stats[b * 64 + ch];
        const float* src = A + ((size_t)(b * 64 + ch)) * S_LEN + n0 + part * 32;
        uint* dst = (uint*)(sX + ch * XP2 + part * 32);
#pragma unroll
        for (int i = 0; i < 8; ++i) {
            float4 v = *(const float4*)(src + 4 * i);
            v.x = (v.x - st.x) * st.y; v.y = (v.y - st.x) * st.y;
            v.z = (v.z - st.x) * st.y; v.w = (v.w - st.x) * st.y;
            dst[2 * i]     = pack2bf(v.x, v.y);
            dst[2 * i + 1] = pack2bf(v.z, v.w);
        }
    }
    __syncthreads();

    const int w = tid >> 6, l = tid & 63, g = l >> 4, c = l & 15;

    // GEMM1 + gelu -> sMid (wave-private rows)
#pragma unroll
    for (int tt = 0; tt < 2; ++tt) {
        const int nl = 32 * w + 16 * tt + c;
        bf16x8 xb[2];
#pragma unroll
        for (int kk = 0; kk < 2; ++kk)
#pragma unroll
            for (int j = 0; j < 8; ++j)
                xb[kk][j] = (short)sX[(kk * 32 + 8 * g + j) * XP2 + nl];
        f32x4 acc1[8];
#pragma unroll
        for (int mt = 0; mt < 8; ++mt) {
            float4 bv = *(const float4*)(b1 + 16 * mt + 4 * g);
            acc1[mt][0] = bv.x; acc1[mt][1] = bv.y; acc1[mt][2] = bv.z; acc1[mt][3] = bv.w;
        }
#pragma unroll
        for (int kk = 0; kk < 2; ++kk)
#pragma unroll
            for (int mt = 0; mt < 8; ++mt) {
                bf16x8 af = *(const bf16x8*)(W1bf + (16 * mt + c) * 64 + kk * 32 + 8 * g);
                acc1[mt] = __builtin_amdgcn_mfma_f32_16x16x32_bf16(af, xb[kk], acc1[mt], 0, 0, 0);
            }
#pragma unroll
        for (int mt = 0; mt < 8; ++mt) {
            uint* mp = (uint*)(sMid + nl * MP2 + 16 * mt + 4 * g);
            mp[0] = pack2bf(gelu1(acc1[mt][0]), gelu1(acc1[mt][1]));
            mp[1] = pack2bf(gelu1(acc1[mt][2]), gelu1(acc1[mt][3]));
        }
    }

    // GEMM2 (K=128) + residual epilogue
#pragma unroll
    for (int tt = 0; tt < 2; ++tt) {
        const int nl = 32 * w + 16 * tt + c;
        bf16x8 mb[4];
#pragma unroll
        for (int kk = 0; kk < 4; ++kk)
            mb[kk] = *(bf16x8*)(sMid + nl * MP2 + kk * 32 + 8 * g);
        f32x4 acc2[4];
#pragma unroll
        for (int mt = 0; mt < 4; ++mt) {
            float4 bv = *(const float4*)(b2 + 16 * mt + 4 * g);
            acc2[mt][0] = bv.x; acc2[mt][1] = bv.y; acc2[mt][2] = bv.z; acc2[mt][3] = bv.w;
        }
#pragma unroll
        for (int kk = 0; kk < 4; ++kk)
#pragma unroll
            for (int mt = 0; mt < 4; ++mt) {
                bf16x8 af = *(const bf16x8*)(W2bf + (16 * mt + c) * 128 + kk * 32 + 8 * g);
                acc2[mt] = __builtin_amdgcn_mfma_f32_16x16x32_bf16(af, mb[kk], acc2[mt], 0, 0, 0);
            }
#pragma unroll
        for (int mt = 0; mt < 4; ++mt)
#pragma unroll
            for (int r = 0; r < 4; ++r) {
                int m = 16 * mt + 4 * g + r;
                float* p = A + ((size_t)(b * 64 + m)) * S_LEN + n0 + nl;
                *p = acc2[mt][r] + *p;
            }
    }
}

// ---------------- fused head: out = W2 * gelu(W1 * A + b1) + b2 (bf16 MFMA) ----------
#define HXP 66
#define HMP 40

__global__ __launch_bounds__(256) void head_kernel(const float* __restrict__ A,
                                                   float* __restrict__ out,
                                                   const ushort* __restrict__ W1bf,  // 32x64
                                                   const float* __restrict__ b1,
                                                   const ushort* __restrict__ W2bf,  // 64x32
                                                   const float* __restrict__ b2) {
    __shared__ ushort sW1[32 * 72];
    __shared__ ushort sW2[64 * HMP];
    __shared__ ushort sX [64 * HXP];
    __shared__ ushort sMid[64 * HMP];
    const int b = blockIdx.y, n0 = blockIdx.x * 64, tid = threadIdx.x;
    {   // W1: 32x64 copy
        int row = tid >> 3, q = tid & 7;
        *(uint4*)(sW1 + row * 72 + q * 8) = *(const uint4*)(W1bf + row * 64 + q * 8);
    }
    {   // W2: 64x32 copy
        int row = tid >> 2, q = tid & 3;
        *(uint4*)(sW2 + row * HMP + q * 8) = *(const uint4*)(W2bf + row * 32 + q * 8);
    }
    {   // X: 64ch x 64pos (no norm)
        int ch = tid >> 2, part = tid & 3;
        const float* src = A + ((size_t)(b * 64 + ch)) * S_LEN + n0 + part * 16;
        uint* dst = (uint*)(sX + ch * HXP + part * 16);
#pragma unroll
        for (int i = 0; i < 4; ++i) {
            float4 v = *(const float4*)(src + 4 * i);
            dst[2 * i] = pack2bf(v.x, v.y); dst[2 * i + 1] = pack2bf(v.z, v.w);
        }
    }
    __syncthreads();
    const int w = tid >> 6, l = tid & 63, g = l >> 4, c = l & 15;
    const int nl = 16 * w + c;
    bf16x8 xb[2];
#pragma unroll
    for (int kk = 0; kk < 2; ++kk)
#pragma unroll
        for (int j = 0; j < 8; ++j)
            xb[kk][j] = (short)sX[(kk * 32 + 8 * g + j) * HXP + nl];
    f32x4 acc1[2];
#pragma unroll
    for (int mt = 0; mt < 2; ++mt) {
        float4 bv = *(const float4*)(b1 + 16 * mt + 4 * g);
        acc1[mt][0] = bv.x; acc1[mt][1] = bv.y; acc1[mt][2] = bv.z; acc1[mt][3] = bv.w;
    }
#pragma unroll
    for (int kk = 0; kk < 2; ++kk)
#pragma unroll
        for (int mt = 0; mt < 2; ++mt) {
            bf16x8 af = *(bf16x8*)(sW1 + (16 * mt + c) * 72 + kk * 32 + 8 * g);
            acc1[mt] = __builtin_amdgcn_mfma_f32_16x16x32_bf16(af, xb[kk], acc1[mt], 0, 0, 0);
        }
#pragma unroll
    for (int mt = 0; mt < 2; ++mt)
#pragma unroll
        for (int r = 0; r < 4; ++r)
            sMid[nl * HMP + 16 * mt + 4 * g + r] = f2bf(gelu1(acc1[mt][r]));
    bf16x8 mb = *(bf16x8*)(sMid + nl * HMP + 8 * g);
    f32x4 acc2[4];
#pragma unroll
    for (int mt = 0; mt < 4; ++mt) {
        float4 bv = *(const float4*)(b2 + 16 * mt + 4 * g);
        acc2[mt][0] = bv.x; acc2[mt][1] = bv.y; acc2[mt][2] = bv.z; acc2[mt][3] = bv.w;
    }
#pragma unroll
    for (int mt = 0; mt < 4; ++mt) {
        bf16x8 af = *(bf16x8*)(sW2 + (16 * mt + c) * HMP + 8 * g);
        acc2[mt] = __builtin_amdgcn_mfma_f32_16x16x32_bf16(af, mb, acc2[mt], 0, 0, 0);
    }
#pragma unroll
    for (int mt = 0; mt < 4; ++mt)
#pragma unroll
        for (int r = 0; r < 4; ++r) {
            int m = 16 * mt + 4 * g + r;
            out[((size_t)(b * 64 + m)) * S_LEN + n0 + nl] = acc2[mt][r];
        }
}

// ---------------- DWT core ----------------
__device__ __forceinline__ void dwt8_core(const float* __restrict__ xb,
                                          float* __restrict__ lo, float* __restrict__ hi) {
#pragma unroll
    for (int j = 0; j < 8; ++j) {
        float l0 = 0.f, h0 = 0.f;
#pragma unroll
        for (int k = 0; k < 16; ++k) {
            float v = xb[2 * j + k + 2];
            l0 = fmaf(v, c_dlo[15 - k], l0);
            h0 = fmaf(v, c_dhi[15 - k], h0);
        }
        lo[j] = l0; hi[j] = h0;
    }
}

__device__ __forceinline__ void dwt_lds_v2(const float* __restrict__ in, int Sin,
                                           float* __restrict__ aout,
                                           float* __restrict__ dout_g, int Lout, int tid) {
    const int NT = (Lout + 7) >> 3;
    for (int g = tid; g < NT; g += 256) {
        float xb[32];
        const int base = 16 * g - 16;
        if (base >= 0 && base + 32 <= Sin) {
#pragma unroll
            for (int q = 0; q < 8; ++q)
                *(float4*)(xb + 4 * q) = *(const float4*)(in + base + 4 * q);
        } else {
#pragma unroll
            for (int loc = 0; loc < 32; ++loc) {
                int i = base + loc;
                i = (i < 0) ? (-1 - i) : i;
                i = (i >= Sin) ? (2 * Sin - 1 - i) : i;
                xb[loc] = in[i];
            }
        }
        float lo[8], hi[8];
        dwt8_core(xb, lo, hi);
        const int t0 = 8 * g;
        if (t0 + 8 <= Lout) {
            *(float4*)(aout + t0)     = make_float4(lo[0], lo[1], lo[2], lo[3]);
            *(float4*)(aout + t0 + 4) = make_float4(lo[4], lo[5], lo[6], lo[7]);
        } else {
#pragma unroll
            for (int j = 0; j < 8; ++j) if (t0 + j < Lout) aout[t0 + j] = lo[j];
        }
        store4g(dout_g, t0,     Lout, make_float4(hi[0], hi[1], hi[2], hi[3]));
        store4g(dout_g, t0 + 4, Lout, make_float4(hi[4], hi[5], hi[6], hi[7]));
    }
}

__global__ __launch_bounds__(256) void dwt_full_kernel(const float* __restrict__ A,
                                                       const float2* __restrict__ stats,
                                                       float* __restrict__ d1,
                                                       float* __restrict__ d2,
                                                       float* __restrict__ d3,
                                                       float* __restrict__ d4,
                                                       float* __restrict__ a4) {
    __shared__ float bufA[4104];
    __shared__ float bufB[2060];
    const int row = blockIdx.x;
    const int tid = threadIdx.x;
    const float2 st = stats[row];
    const float* x = A + (size_t)row * S_LEN;
    float* d1r = d1 + (size_t)row * LP1;

    for (int g = tid; g < 513; g += 256) {
        const int base = 16 * g - 16;
        float xb[32];
        if (base >= 0 && base + 32 <= S_LEN) {
#pragma unroll
            for (int q = 0; q < 8; ++q) {
                float4 v = *(const float4*)(x + base + 4 * q);
                v.x = (v.x - st.x) * st.y; v.y = (v.y - st.x) * st.y;
                v.z = (v.z - st.x) * st.y; v.w = (v.w - st.x) * st.y;
                *(float4*)(xb + 4 * q) = v;
            }
        } else {
#pragma unroll
            for (int loc = 0; loc < 32; ++loc) {
                int i = base + loc;
                i = (i < 0) ? (-1 - i) : i;
                i = (i >= S_LEN) ? (2 * S_LEN - 1 - i) : i;
                xb[loc] = (x[i] - st.x) * st.y;
            }
        }
        float lo[8], hi[8];
        dwt8_core(xb, lo, hi);
        const int t0 = 8 * g;
#pragma unroll
        for (int j = 0; j < 8; ++j)
            if (t0 + j < L1v) bufA[t0 + j] = lo[j];
        store4g(d1r, t0,     L1v, make_float4(hi[0], hi[1], hi[2], hi[3]));
        store4g(d1r, t0 + 4, L1v, make_float4(hi[4], hi[5], hi[6], hi[7]));
    }
    __syncthreads();
    dwt_lds_v2(bufA, L1v, bufB, d2 + (size_t)row * LP2, L2v, tid);
    __syncthreads();
    dwt_lds_v2(bufB, L2v, bufA, d3 + (size_t)row * LP3, L3v, tid);
    __syncthreads();
    dwt_lds_v2(bufA, L3v, bufB, d4 + (size_t)row * LP4, L4v, tid);
    __syncthreads();
    float* a4r = a4 + (size_t)row * LP4;
    for (int i = tid; i < 132; i += 256)
        *(float4*)(a4r + 4 * i) = *(const float4*)(bufB + 4 * i);
}

// ---------------- IDWT ----------------
__device__ __forceinline__ void idwt8_regs(const float* __restrict__ a,
                                           const float* __restrict__ d,
                                           int g, int Lc, float* __restrict__ y) {
    float av[12], dv[12];
    const int m0 = 4 * g;
    if (m0 + 12 <= Lc) {
#pragma unroll
        for (int q = 0; q < 3; ++q) {
            *(float4*)(av + 4 * q) = *(const float4*)(a + m0 + 4 * q);
            *(float4*)(dv + 4 * q) = *(const float4*)(d + m0 + 4 * q);
        }
    } else {
#pragma unroll
        for (int jj = 0; jj < 12; ++jj) {
            int m = m0 + jj;
            bool ok = (m < Lc);
            av[jj] = ok ? a[m] : 0.f;
            dv[jj] = ok ? d[m] : 0.f;
        }
    }
#pragma unroll
    for (int e = 0; e < 4; ++e) {
        float ye = 0.f, yo = 0.f;
#pragma unroll
        for (int j = 0; j < 8; ++j) {
            ye = fmaf(av[e + j], c_dlo[2 * j + 1], ye);
            ye = fmaf(dv[e + j], c_dlo[14 - 2 * j], ye);
            yo = fmaf(av[e + j], c_dlo[2 * j], yo);
            yo = fmaf(dv[e + j], -c_dlo[15 - 2 * j], yo);
        }
        y[2 * e] = ye;
        y[2 * e + 1] = yo;
    }
}

__device__ __forceinline__ void idwt_lds_v2(const float* __restrict__ a,
                                            const float* __restrict__ d,
                                            int Lc, int Lout, float* __restrict__ out, int tid) {
    const int NT = (Lout + 7) >> 3;
    for (int g = tid; g < NT; g += 256) {
        float y[8];
        idwt8_regs(a, d, g, Lc, y);
        const int t0 = 8 * g;
        if (t0 + 8 <= Lout) {
            *(float4*)(out + t0)     = make_float4(y[0], y[1], y[2], y[3]);
            *(float4*)(out + t0 + 4) = make_float4(y[4], y[5], y[6], y[7]);
        } else {
#pragma unroll
            for (int j = 0; j < 8; ++j) if (t0 + j < Lout) out[t0 + j] = y[j];
        }
    }
}

__device__ __forceinline__ void gload_lds(const float* __restrict__ src, int Lv,
                                          float* __restrict__ dst, int tid) {
    const int NG = (Lv + 3) >> 2;
    for (int i = tid; i < NG; i += 256)
        *(float4*)(dst + 4 * i) = load4g(src, 4 * i, Lv);
}

__global__ __launch_bounds__(256) void idwt_full_kernel(const float* __restrict__ a4,
                                                        const float* __restrict__ d4,
                                                        const float* __restrict__ d3,
                                                        const float* __restrict__ d2,
                                                        const float* __restrict__ d1,
                                                        float* __restrict__ h,
                                                        const float* __restrict__ xs,
                                                        float2* __restrict__ statsOut) {
    __shared__ float bufY[4104];
    __shared__ float bufA[4104];
    __shared__ float bufD[4104];
    const int row = blockIdx.x;
    const int tid = threadIdx.x;

    gload_lds(a4 + (size_t)row * LP4, L4v, bufA, tid);
    gload_lds(d4 + (size_t)row * LP4, L4v, bufD, tid);
    __syncthreads();
    idwt_lds_v2(bufA, bufD, L4v, 1038, bufY, tid);
    __syncthreads();
    gload_lds(d3 + (size_t)row * LP3, L3v, bufD, tid);
    __syncthreads();
    idwt_lds_v2(bufY, bufD, L3v, 2060, bufA, tid);
    __syncthreads();
    gload_lds(d2 + (size_t)row * LP2, L2v, bufD, tid);
    __syncthreads();
    idwt_lds_v2(bufA, bufD, L2v, 4104, bufY, tid);
    __syncthreads();
    gload_lds(d1 + (size_t)row * LP1, L1v, bufD, tid);
    __syncthreads();

    float* hrow = h + (size_t)row * S_LEN;
    const float* srow = xs + (size_t)row * S_LEN;
    float s = 0.f, ss = 0.f;
#pragma unroll
    for (int it = 0; it < 4; ++it) {
        const int g = it * 256 + tid;
        float y[8];
        idwt8_regs(bufY, bufD, g, L1v, y);
        const int t0 = 8 * g;
#pragma unroll
        for (int q = 0; q < 2; ++q) {
            float4 sv = *(const float4*)(srow + t0 + 4 * q);
            float4 hv = *(const float4*)(hrow + t0 + 4 * q);
            hv.x += gelu1(y[4 * q + 0] + sv.x);
            hv.y += gelu1(y[4 * q + 1] + sv.y);
            hv.z += gelu1(y[4 * q + 2] + sv.z);
            hv.w += gelu1(y[4 * q + 3] + sv.w);
            *(float4*)(hrow + t0 + 4 * q) = hv;
            s += hv.x + hv.y + hv.z + hv.w;
            ss = fmaf(hv.x, hv.x, fmaf(hv.y, hv.y, fmaf(hv.z, hv.z, fmaf(hv.w, hv.w, ss))));
        }
    }
    for (int off = 32; off > 0; off >>= 1) {
        s  += __shfl_down(s, off, 64);
        ss += __shfl_down(ss, off, 64);
    }
    __syncthreads();
    int lane = tid & 63, wv = tid >> 6;
    if (lane == 0) { bufA[wv] = s; bufA[4 + wv] = ss; }
    __syncthreads();
    if (tid == 0) {
        float tot  = bufA[0] + bufA[1] + bufA[2] + bufA[3];
        float tot2 = bufA[4] + bufA[5] + bufA[6] + bufA[7];
        float mean = tot * (1.0f / S_LEN);
        float var  = tot2 * (1.0f / S_LEN) - mean * mean;
        statsOut[row] = make_float2(mean, rsqrtf(var + 1e-5f));
    }
}

extern "C" void kernel_launch(void* const* d_in, const int* in_sizes, int n_in,
                              void* d_out, int out_size, void* d_ws, size_t ws_size,
                              hipStream_t stream) {
    const float* x       = (const float*)d_in[0];
    const float* lift_w  = (const float*)d_in[1];
    const float* lift_b  = (const float*)d_in[2];
    const float* blk_w_w = (const float*)d_in[3];
    const float* blk_w_b = (const float*)d_in[4];
    const float* blk_ca_w= (const float*)d_in[5];
    const float* blk_ca_b= (const float*)d_in[6];
    const float* blk_cd_w= (const float*)d_in[7];
    const float* blk_cd_b= (const float*)d_in[8];
    const float* blk_m1_w= (const float*)d_in[9];
    const float* blk_m1_b= (const float*)d_in[10];
    const float* blk_m2_w= (const float*)d_in[11];
    const float* blk_m2_b= (const float*)d_in[12];
    const float* p1_w    = (const float*)d_in[13];
    const float* p1_b    = (const float*)d_in[14];
    const float* p2_w    = (const float*)d_in[15];
    const float* p2_b    = (const float*)d_in[16];

    float* ws = (float*)d_ws;
    const size_t T32 = (size_t)NBC * S_LEN;
    float* A  = ws;                                  // h / xo (residual stream)
    float* Cc = ws + 2 * T32;                        // xs (conv out)
    float* d1 = ws + 4 * T32;
    float* d2 = d1 + (size_t)NBC * LP1;
    float* d3 = d2 + (size_t)NBC * LP2;
    float* d4 = d3 + (size_t)NBC * LP3;
    float* ap0 = d4 + (size_t)NBC * LP4;
    float* ap1 = ap0 + (size_t)NBC * 4104;
    float2* statsBuf = (float2*)(ap1 + (size_t)NBC * 4104);
    ushort* wbuf = (ushort*)(statsBuf + NBC);

    dim3 blk(256);

    prep_kernel<<<(WTOT + 255) / 256, blk, 0, stream>>>(blk_w_w, blk_m1_w, blk_m2_w,
                                                        blk_cd_w, blk_ca_w, p1_w, p2_w, wbuf);
    lift_kernel<<<(NBC * S_LEN) / 256, blk, 0, stream>>>(x, lift_w, lift_b, A);

    for (int i = 0; i < 4; ++i) {
        const float* w_b  = blk_w_b  + (size_t)i * 64;
        const float* ca_b = blk_ca_b + (size_t)i * 64;
        const float* cd_b = blk_cd_b + (size_t)i * 4 * 64;
        const float* m1_b = blk_m1_b + (size_t)i * 128;
        const float* m2_b = blk_m2_b + (size_t)i * 64;
        const ushort* convbf = wbuf + OFF_CONV + (size_t)i * 12288;
        const ushort* m1bf   = wbuf + OFF_M1   + (size_t)i * 8192;
        const ushort* m2bf   = wbuf + OFF_M2   + (size_t)i * 8192;
        const ushort* cdbf   = wbuf + OFF_CD   + (size_t)i * 16384;
        const ushort* cabf   = wbuf + OFF_CA   + (size_t)i * 4096;

        stats_kernel<<<NBC, blk, 0, stream>>>(A, statsBuf);
        conv3_mfma_kernel<<<dim3(S_LEN / 128, B_N), blk, 0, stream>>>(A, Cc, convbf, w_b, statsBuf);
        dwt_full_kernel<<<NBC, blk, 0, stream>>>(A, statsBuf, d1, d2, d3, d4, ap1);

        wmix_kernel<<<dim3(69, B_N), blk, 0, stream>>>(d1, d2, d3, d4, ap1,
                                                       cdbf, cd_b, cabf, ca_b);

        idwt_full_kernel<<<NBC, blk, 0, stream>>>(ap1, d4, d3, d2, d1, A, Cc, statsBuf);
        mlp_kernel<<<dim3(S_LEN / 128, B_N), blk, 0, stream>>>(A, statsBuf, m1bf, m1_b, m2bf, m2_b);
    }

    head_kernel<<<dim3(S_LEN / 64, B_N), blk, 0, stream>>>(A, (float*)d_out,
                                                           wbuf + OFF_P1, p1_b,
                                                           wbuf + OFF_P2, p2_b);
}

// Round 9
// 681.990 us; speedup vs baseline: 1.2306x; 1.2306x over previous
//
#include <hip/hip_runtime.h>
#include <math.h>

#define S_LEN 8192
#define B_N   16
#define NBC   1024          // B*C rows
#define L1v 4103
#define L2v 2059
#define L3v 1037
#define L4v 526
// bf16 buffer row pitches (ushorts, multiples of 8 for 16B alignment)
#define LB1 4104
#define LB2 2064
#define LB3 1040
#define LB4 528

// bf16 weight buffer offsets (ushorts)
#define OFF_CONV 0          // 4 x 12288  [o][tap*64+c]
#define OFF_M1   49152      // 4 x 8192   [m][k]
#define OFF_M2   81920      // 4 x 8192
#define OFF_CD   114688     // 4 x 16384  [lvl][o][c]
#define OFF_CA   180224     // 4 x 4096
#define OFF_P1   196608     // 2048
#define OFF_P2   198656     // 2048
#define WTOT     200704

typedef __attribute__((ext_vector_type(8))) short bf16x8;
typedef __attribute__((ext_vector_type(4))) float f32x4;

__constant__ float c_dlo[16] = {
    -0.0033824159510061256f, -0.0005421323317911481f,  0.03169508781149298f,
     0.007607487324917605f,  -0.1432942383508097f,    -0.061273359067658524f,
     0.4813596512583722f,     0.7771857517005235f,     0.3644418948353314f,
    -0.05194583810770904f,   -0.027219029917056003f,   0.049137179673607506f,
     0.003808752013890615f,  -0.01495225833704823f,   -0.0003029205147213668f,
     0.0018899503327594609f
};
__constant__ float c_dhi[16] = {
    -0.0018899503327594609f, -0.0003029205147213668f,  0.01495225833704823f,
     0.003808752013890615f,  -0.049137179673607506f,  -0.027219029917056003f,
     0.05194583810770904f,    0.3644418948353314f,    -0.7771857517005235f,
     0.4813596512583722f,     0.061273359067658524f,  -0.1432942383508097f,
    -0.007607487324917605f,   0.03169508781149298f,    0.0005421323317911481f,
    -0.0033824159510061256f
};

__device__ __forceinline__ float gelu1(float x) {
    return 0.5f * x * (1.0f + erff(x * 0.70710678118654752f));
}
__device__ __forceinline__ float4 load4g(const float* __restrict__ row, int l, int L) {
    float4 v;
    if (l >= 0 && l + 3 < L) {
        v = *(const float4*)(row + l);
    } else {
        v.x = (l     >= 0 && l     < L) ? row[l]     : 0.f;
        v.y = (l + 1 >= 0 && l + 1 < L) ? row[l + 1] : 0.f;
        v.z = (l + 2 >= 0 && l + 2 < L) ? row[l + 2] : 0.f;
        v.w = (l + 3 >= 0 && l + 3 < L) ? row[l + 3] : 0.f;
    }
    return v;
}
__device__ __forceinline__ ushort f2bf(float f) {
    uint u = __float_as_uint(f);
    u += 0x7fffu + ((u >> 16) & 1u);
    return (ushort)(u >> 16);
}
__device__ __forceinline__ uint pack2bf(float a, float b) {
    return (uint)f2bf(a) | ((uint)f2bf(b) << 16);
}
__device__ __forceinline__ float bfu(ushort u) {
    return __uint_as_float(((uint)u) << 16);
}

// ---------------- one-time weight prep: f32 -> bf16 (conv reordered) ----------------
__global__ __launch_bounds__(256) void prep_kernel(const float* __restrict__ convW,
                                                   const float* __restrict__ m1,
                                                   const float* __restrict__ m2,
                                                   const float* __restrict__ cd,
                                                   const float* __restrict__ ca,
                                                   const float* __restrict__ p1,
                                                   const float* __restrict__ p2,
                                                   ushort* __restrict__ wbuf) {
    int idx = blockIdx.x * 256 + threadIdx.x;
    if (idx >= WTOT) return;
    float v;
    if (idx < OFF_M1) {
        int i = idx / 12288, r = idx % 12288;
        int o = r / 192, k = r % 192;
        int tap = k >> 6, c = k & 63;
        v = convW[i * 12288 + o * 192 + c * 3 + tap];
    } else if (idx < OFF_M2) v = m1[idx - OFF_M1];
    else if (idx < OFF_CD)   v = m2[idx - OFF_M2];
    else if (idx < OFF_CA)   v = cd[idx - OFF_CD];
    else if (idx < OFF_P1)   v = ca[idx - OFF_CA];
    else if (idx < OFF_P2)   v = p1[idx - OFF_P1];
    else                     v = p2[idx - OFF_P2];
    wbuf[idx] = f2bf(v);
}

// ---------------- lift ----------------
__global__ __launch_bounds__(256) void lift_kernel(const float* __restrict__ x,
                                                   const float* __restrict__ w,
                                                   const float* __restrict__ bias,
                                                   float* __restrict__ out) {
    int idx = blockIdx.x * 256 + threadIdx.x;
    int s = idx & (S_LEN - 1);
    int r = idx >> 13;
    int o = r & 63;
    int b = r >> 6;
    float g = -1.0f + 2.0f * (float)s / (float)(S_LEN - 1);
    out[idx] = fmaf(w[o * 2 + 0], x[b * S_LEN + s], fmaf(w[o * 2 + 1], g, bias[o]));
}

// ---------------- row stats: mean + rsqrt(var+eps) ----------------
__global__ __launch_bounds__(256) void stats_kernel(const float* __restrict__ in,
                                                    float2* __restrict__ stats) {
    const int base = blockIdx.x * S_LEN;
    const int tid = threadIdx.x;
    float s = 0.f, ss = 0.f;
#pragma unroll
    for (int i = 0; i < 8; ++i) {
        float4 v = *(const float4*)(in + base + (tid + i * 256) * 4);
        s += v.x + v.y + v.z + v.w;
        ss = fmaf(v.x, v.x, fmaf(v.y, v.y, fmaf(v.z, v.z, fmaf(v.w, v.w, ss))));
    }
    for (int off = 32; off > 0; off >>= 1) {
        s  += __shfl_down(s, off, 64);
        ss += __shfl_down(ss, off, 64);
    }
    __shared__ float sh[8];
    int lane = tid & 63, wv = tid >> 6;
    if (lane == 0) { sh[wv] = s; sh[4 + wv] = ss; }
    __syncthreads();
    if (tid == 0) {
        float tot  = sh[0] + sh[1] + sh[2] + sh[3];
        float tot2 = sh[4] + sh[5] + sh[6] + sh[7];
        float mean = tot * (1.0f / S_LEN);
        float var  = tot2 * (1.0f / S_LEN) - mean * mean;
        stats[blockIdx.x] = make_float2(mean, rsqrtf(var + 1e-5f));
    }
}

// ---------------- conv1d k=3 via bf16 MFMA; writes xs as bf16 -------------
#define CWP 200
#define CXP 72

__global__ __launch_bounds__(256) void conv3_mfma_kernel(const float* __restrict__ in,
                                                         ushort* __restrict__ out,
                                                         const ushort* __restrict__ Wbf,
                                                         const float* __restrict__ bias,
                                                         const float2* __restrict__ stats) {
    __shared__ ushort sW[64 * CWP];
    __shared__ ushort sXt[144 * CXP];
    const int b = blockIdx.y;
    const int n0 = blockIdx.x * 128;
    const int tid = threadIdx.x;

    {   // stage pre-converted W: plain 16B copies
        const int o = tid >> 2, q = tid & 3;
        const uint4* src = (const uint4*)(Wbf + o * 192 + q * 48);
        uint4* dst = (uint4*)(sW + o * CWP + q * 48);
#pragma unroll
        for (int i = 0; i < 6; ++i) dst[i] = src[i];
    }
    {   // stage x^T normalized (zero outside [0,S_LEN))
        const int ch = tid >> 2, q = tid & 3;
        const int rowi = b * 64 + ch;
        const float2 st = stats[rowi];
        const float* row = in + (size_t)rowi * S_LEN;
#pragma unroll
        for (int i = 0; i < 9; ++i) {
            int p = q * 36 + i * 4;
            int l = n0 - 8 + p;
            float4 v;
            if (l >= 0 && l + 3 < S_LEN) {
                v = *(const float4*)(row + l);
                v.x = (v.x - st.x) * st.y; v.y = (v.y - st.x) * st.y;
                v.z = (v.z - st.x) * st.y; v.w = (v.w - st.x) * st.y;
            } else {
                v.x = (l     >= 0 && l     < S_LEN) ? (row[l]     - st.x) * st.y : 0.f;
                v.y = (l + 1 >= 0 && l + 1 < S_LEN) ? (row[l + 1] - st.x) * st.y : 0.f;
                v.z = (l + 2 >= 0 && l + 2 < S_LEN) ? (row[l + 2] - st.x) * st.y : 0.f;
                v.w = (l + 3 >= 0 && l + 3 < S_LEN) ? (row[l + 3] - st.x) * st.y : 0.f;
            }
            sXt[(p + 0) * CXP + ch] = f2bf(v.x);
            sXt[(p + 1) * CXP + ch] = f2bf(v.y);
            sXt[(p + 2) * CXP + ch] = f2bf(v.z);
            sXt[(p + 3) * CXP + ch] = f2bf(v.w);
        }
    }
    __syncthreads();

    const int w = tid >> 6, l = tid & 63, g = l >> 4, c = l & 15;
    f32x4 acc[2][4];
#pragma unroll
    for (int mt = 0; mt < 4; ++mt) {
        float4 bv = *(const float4*)(bias + 16 * mt + 4 * g);
#pragma unroll
        for (int t = 0; t < 2; ++t) {
            acc[t][mt][0] = bv.x; acc[t][mt][1] = bv.y;
            acc[t][mt][2] = bv.z; acc[t][mt][3] = bv.w;
        }
    }
#pragma unroll
    for (int kk = 0; kk < 6; ++kk) {
        const int tap = kk >> 1;
        bf16x8 af[4];
#pragma unroll
        for (int mt = 0; mt < 4; ++mt)
            af[mt] = *(bf16x8*)(sW + (16 * mt + c) * CWP + kk * 32 + 8 * g);
#pragma unroll
        for (int t = 0; t < 2; ++t) {
            const int nl = 32 * w + 16 * t + c;
            const int p = nl + tap + 7;
            bf16x8 xb = *(bf16x8*)(sXt + p * CXP + (kk & 1) * 32 + 8 * g);
#pragma unroll
            for (int mt = 0; mt < 4; ++mt)
                acc[t][mt] = __builtin_amdgcn_mfma_f32_16x16x32_bf16(af[mt], xb, acc[t][mt], 0, 0, 0);
        }
    }
#pragma unroll
    for (int t = 0; t < 2; ++t) {
        const int nl = 32 * w + 16 * t + c;
#pragma unroll
        for (int mt = 0; mt < 4; ++mt)
#pragma unroll
            for (int r = 0; r < 4; ++r) {
                int m = 16 * mt + 4 * g + r;
                out[((size_t)(b * 64 + m)) * S_LEN + n0 + nl] = f2bf(acc[t][mt][r]);
            }
    }
}

// ---------------- consolidated wavelet-domain channel mix (bf16 in/out, MFMA) --------
#define WMP 72
#define WXP 136

__global__ __launch_bounds__(256) void wmix_kernel(ushort* __restrict__ d1,
                                                   ushort* __restrict__ d2,
                                                   ushort* __restrict__ d3,
                                                   ushort* __restrict__ d4,
                                                   ushort* __restrict__ a4,
                                                   const ushort* __restrict__ cdbf,
                                                   const float* __restrict__ cd_b,
                                                   const ushort* __restrict__ cabf,
                                                   const float* __restrict__ ca_b) {
    __shared__ ushort sW[64 * WMP];
    __shared__ ushort sX[64 * WXP];
    const int b = blockIdx.y;
    const int t = blockIdx.x;
    ushort* buf; const ushort* W; const float* bias; int L, LP, l0;
    if (t < 33)      { buf = d1; W = cdbf + 3 * 4096; bias = cd_b + 3 * 64; L = L1v; LP = LB1; l0 = t * 128; }
    else if (t < 50) { buf = d2; W = cdbf + 2 * 4096; bias = cd_b + 2 * 64; L = L2v; LP = LB2; l0 = (t - 33) * 128; }
    else if (t < 59) { buf = d3; W = cdbf + 1 * 4096; bias = cd_b + 1 * 64; L = L3v; LP = LB3; l0 = (t - 50) * 128; }
    else if (t < 64) { buf = d4; W = cdbf;            bias = cd_b;          L = L4v; LP = LB4; l0 = (t - 59) * 128; }
    else             { buf = a4; W = cabf;            bias = ca_b;          L = L4v; LP = LB4; l0 = (t - 64) * 128; }
    const int tid = threadIdx.x;
    {   // stage W (64x64 bf16): plain copies
        int row = tid >> 2, q = tid & 3;
        const uint4* src = (const uint4*)(W + row * 64 + q * 16);
        uint4* dst = (uint4*)(sW + row * WMP + q * 16);
        dst[0] = src[0]; dst[1] = src[1];
    }
    {   // stage x tile [ch][128 pos], bf16 copies with bounds
        int ch = tid >> 2, part = tid & 3;
        const ushort* src = buf + ((size_t)(b * 64 + ch)) * LP;
#pragma unroll
        for (int i = 0; i < 4; ++i) {
            int l = l0 + part * 32 + 8 * i;
            ushort* dst = sX + ch * WXP + part * 32 + 8 * i;
            if (l + 8 <= L) {
                *(uint4*)dst = *(const uint4*)(src + l);
            } else {
#pragma unroll
                for (int j = 0; j < 8; ++j)
                    dst[j] = (l + j < L) ? src[l + j] : (ushort)0;
            }
        }
    }
    __syncthreads();
    const int w = tid >> 6, l = tid & 63, g = l >> 4, c = l & 15;
    f32x4 acc[2][4];
#pragma unroll
    for (int mt = 0; mt < 4; ++mt) {
        float4 bv = *(const float4*)(bias + 16 * mt + 4 * g);
#pragma unroll
        for (int tt = 0; tt < 2; ++tt) {
            acc[tt][mt][0] = bv.x; acc[tt][mt][1] = bv.y;
            acc[tt][mt][2] = bv.z; acc[tt][mt][3] = bv.w;
        }
    }
#pragma unroll
    for (int kk = 0; kk < 2; ++kk) {
        bf16x8 af[4];
#pragma unroll
        for (int mt = 0; mt < 4; ++mt)
            af[mt] = *(bf16x8*)(sW + (16 * mt + c) * WMP + kk * 32 + 8 * g);
#pragma unroll
        for (int tt = 0; tt < 2; ++tt) {
            const int nl = 32 * w + 16 * tt + c;
            bf16x8 xb;
#pragma unroll
            for (int j = 0; j < 8; ++j)
                xb[j] = (short)sX[(kk * 32 + 8 * g + j) * WXP + nl];
#pragma unroll
            for (int mt = 0; mt < 4; ++mt)
                acc[tt][mt] = __builtin_amdgcn_mfma_f32_16x16x32_bf16(af[mt], xb, acc[tt][mt], 0, 0, 0);
        }
    }
#pragma unroll
    for (int tt = 0; tt < 2; ++tt) {
        const int nl = 32 * w + 16 * tt + c;
        if (l0 + nl < L) {
#pragma unroll
            for (int mt = 0; mt < 4; ++mt)
#pragma unroll
                for (int r = 0; r < 4; ++r) {
                    int m = 16 * mt + 4 * g + r;
                    buf[((size_t)(b * 64 + m)) * LP + l0 + nl] = f2bf(acc[tt][mt][r]);
                }
        }
    }
}

// ---------------- fused MLP: A += W2*gelu(W1*inorm(A)+b1)+b2, LDS weights from wbuf ------
#define W1P 72
#define W2P 136
#define XP  66
#define MP  136

__global__ __launch_bounds__(256) void mlp_kernel(float* __restrict__ A,
                                                  const float2* __restrict__ stats,
                                                  const ushort* __restrict__ W1bf,
                                                  const float* __restrict__ b1,
                                                  const ushort* __restrict__ W2bf,
                                                  const float* __restrict__ b2) {
    __shared__ ushort sW1[128 * W1P];
    __shared__ ushort sW2[64 * W2P];
    __shared__ ushort sX [64 * XP];
    __shared__ ushort sMid[64 * MP];
    const int b  = blockIdx.y;
    const int n0 = blockIdx.x * 64;
    const int tid = threadIdx.x;

    {   // stage W1 (128 rows x 64 ushorts = 1024 uint4)
#pragma unroll
        for (int e = tid; e < 1024; e += 256) {
            int row = e >> 3, q = e & 7;
            *(uint4*)(sW1 + row * W1P + q * 8) = *(const uint4*)(W1bf + row * 64 + q * 8);
        }
    }
    {   // stage W2 (64 rows x 128 ushorts = 1024 uint4)
#pragma unroll
        for (int e = tid; e < 1024; e += 256) {
            int row = e >> 4, q = e & 15;
            *(uint4*)(sW2 + row * W2P + q * 8) = *(const uint4*)(W2bf + row * 128 + q * 8);
        }
    }
    {   // stage xn tile: normalize A[ch][n0..n0+63] -> bf16 [ch][pos]
        int ch = tid >> 2, part = tid & 3;
        float2 st = stats[b * 64 + ch];
        const float* src = A + ((size_t)(b * 64 + ch)) * S_LEN + n0 + part * 16;
        uint* dst = (uint*)(sX + ch * XP + part * 16);
#pragma unroll
        for (int i = 0; i < 4; ++i) {
            float4 v = *(const float4*)(src + 4 * i);
            v.x = (v.x - st.x) * st.y; v.y = (v.y - st.x) * st.y;
            v.z = (v.z - st.x) * st.y; v.w = (v.w - st.x) * st.y;
            dst[2 * i]     = pack2bf(v.x, v.y);
            dst[2 * i + 1] = pack2bf(v.z, v.w);
        }
    }
    __syncthreads();

    const int w = tid >> 6;
    const int l = tid & 63;
    const int g = l >> 4;
    const int c = l & 15;
    const int nl = 16 * w + c;

    bf16x8 xb[2];
#pragma unroll
    for (int kk = 0; kk < 2; ++kk)
#pragma unroll
        for (int j = 0; j < 8; ++j)
            xb[kk][j] = (short)sX[(kk * 32 + 8 * g + j) * XP + nl];

    f32x4 acc1[8];
#pragma unroll
    for (int mt = 0; mt < 8; ++mt) {
        float4 bv = *(const float4*)(b1 + 16 * mt + 4 * g);
        acc1[mt][0] = bv.x; acc1[mt][1] = bv.y; acc1[mt][2] = bv.z; acc1[mt][3] = bv.w;
    }
#pragma unroll
    for (int kk = 0; kk < 2; ++kk) {
#pragma unroll
        for (int mt = 0; mt < 8; ++mt) {
            bf16x8 af = *(bf16x8*)(sW1 + (16 * mt + c) * W1P + kk * 32 + 8 * g);
            acc1[mt] = __builtin_amdgcn_mfma_f32_16x16x32_bf16(af, xb[kk], acc1[mt], 0, 0, 0);
        }
    }
#pragma unroll
    for (int mt = 0; mt < 8; ++mt) {
        uint* mp = (uint*)(sMid + nl * MP + 16 * mt + 4 * g);
        mp[0] = pack2bf(gelu1(acc1[mt][0]), gelu1(acc1[mt][1]));
        mp[1] = pack2bf(gelu1(acc1[mt][2]), gelu1(acc1[mt][3]));
    }

    bf16x8 mb[4];
#pragma unroll
    for (int kk = 0; kk < 4; ++kk)
        mb[kk] = *(bf16x8*)(sMid + nl * MP + kk * 32 + 8 * g);

    f32x4 acc2[4];
#pragma unroll
    for (int mt = 0; mt < 4; ++mt) {
        float4 bv = *(const float4*)(b2 + 16 * mt + 4 * g);
        acc2[mt][0] = bv.x; acc2[mt][1] = bv.y; acc2[mt][2] = bv.z; acc2[mt][3] = bv.w;
    }
#pragma unroll
    for (int kk = 0; kk < 4; ++kk) {
#pragma unroll
        for (int mt = 0; mt < 4; ++mt) {
            bf16x8 af = *(bf16x8*)(sW2 + (16 * mt + c) * W2P + kk * 32 + 8 * g);
            acc2[mt] = __builtin_amdgcn_mfma_f32_16x16x32_bf16(af, mb[kk], acc2[mt], 0, 0, 0);
        }
    }
#pragma unroll
    for (int mt = 0; mt < 4; ++mt) {
#pragma unroll
        for (int r = 0; r < 4; ++r) {
            int m = 16 * mt + 4 * g + r;
            float* p = A + ((size_t)(b * 64 + m)) * S_LEN + n0 + nl;
            *p = acc2[mt][r] + *p;
        }
    }
}

// ---------------- fused head: out = W2 * gelu(W1 * A + b1) + b2 (bf16 MFMA) ----------
#define HXP 66
#define HMP 40

__global__ __launch_bounds__(256) void head_kernel(const float* __restrict__ A,
                                                   float* __restrict__ out,
                                                   const ushort* __restrict__ W1bf,
                                                   const float* __restrict__ b1,
                                                   const ushort* __restrict__ W2bf,
                                                   const float* __restrict__ b2) {
    __shared__ ushort sW1[32 * 72];
    __shared__ ushort sW2[64 * HMP];
    __shared__ ushort sX [64 * HXP];
    __shared__ ushort sMid[64 * HMP];
    const int b = blockIdx.y, n0 = blockIdx.x * 64, tid = threadIdx.x;
    {
        int row = tid >> 3, q = tid & 7;
        *(uint4*)(sW1 + row * 72 + q * 8) = *(const uint4*)(W1bf + row * 64 + q * 8);
    }
    {
        int row = tid >> 2, q = tid & 3;
        *(uint4*)(sW2 + row * HMP + q * 8) = *(const uint4*)(W2bf + row * 32 + q * 8);
    }
    {
        int ch = tid >> 2, part = tid & 3;
        const float* src = A + ((size_t)(b * 64 + ch)) * S_LEN + n0 + part * 16;
        uint* dst = (uint*)(sX + ch * HXP + part * 16);
#pragma unroll
        for (int i = 0; i < 4; ++i) {
            float4 v = *(const float4*)(src + 4 * i);
            dst[2 * i] = pack2bf(v.x, v.y); dst[2 * i + 1] = pack2bf(v.z, v.w);
        }
    }
    __syncthreads();
    const int w = tid >> 6, l = tid & 63, g = l >> 4, c = l & 15;
    const int nl = 16 * w + c;
    bf16x8 xb[2];
#pragma unroll
    for (int kk = 0; kk < 2; ++kk)
#pragma unroll
        for (int j = 0; j < 8; ++j)
            xb[kk][j] = (short)sX[(kk * 32 + 8 * g + j) * HXP + nl];
    f32x4 acc1[2];
#pragma unroll
    for (int mt = 0; mt < 2; ++mt) {
        float4 bv = *(const float4*)(b1 + 16 * mt + 4 * g);
        acc1[mt][0] = bv.x; acc1[mt][1] = bv.y; acc1[mt][2] = bv.z; acc1[mt][3] = bv.w;
    }
#pragma unroll
    for (int kk = 0; kk < 2; ++kk)
#pragma unroll
        for (int mt = 0; mt < 2; ++mt) {
            bf16x8 af = *(bf16x8*)(sW1 + (16 * mt + c) * 72 + kk * 32 + 8 * g);
            acc1[mt] = __builtin_amdgcn_mfma_f32_16x16x32_bf16(af, xb[kk], acc1[mt], 0, 0, 0);
        }
#pragma unroll
    for (int mt = 0; mt < 2; ++mt)
#pragma unroll
        for (int r = 0; r < 4; ++r)
            sMid[nl * HMP + 16 * mt + 4 * g + r] = f2bf(gelu1(acc1[mt][r]));
    bf16x8 mb = *(bf16x8*)(sMid + nl * HMP + 8 * g);
    f32x4 acc2[4];
#pragma unroll
    for (int mt = 0; mt < 4; ++mt) {
        float4 bv = *(const float4*)(b2 + 16 * mt + 4 * g);
        acc2[mt][0] = bv.x; acc2[mt][1] = bv.y; acc2[mt][2] = bv.z; acc2[mt][3] = bv.w;
    }
#pragma unroll
    for (int mt = 0; mt < 4; ++mt) {
        bf16x8 af = *(bf16x8*)(sW2 + (16 * mt + c) * HMP + 8 * g);
        acc2[mt] = __builtin_amdgcn_mfma_f32_16x16x32_bf16(af, mb, acc2[mt], 0, 0, 0);
    }
#pragma unroll
    for (int mt = 0; mt < 4; ++mt)
#pragma unroll
        for (int r = 0; r < 4; ++r) {
            int m = 16 * mt + 4 * g + r;
            out[((size_t)(b * 64 + m)) * S_LEN + n0 + nl] = acc2[mt][r];
        }
}

// ---------------- DWT core ----------------
__device__ __forceinline__ void dwt8_core(const float* __restrict__ xb,
                                          float* __restrict__ lo, float* __restrict__ hi) {
#pragma unroll
    for (int j = 0; j < 8; ++j) {
        float l0 = 0.f, h0 = 0.f;
#pragma unroll
        for (int k = 0; k < 16; ++k) {
            float v = xb[2 * j + k + 2];
            l0 = fmaf(v, c_dlo[15 - k], l0);
            h0 = fmaf(v, c_dhi[15 - k], h0);
        }
        lo[j] = l0; hi[j] = h0;
    }
}

__device__ __forceinline__ void store_bf8(ushort* __restrict__ dst, int t0, int Lout,
                                          const float* __restrict__ v) {
    if (t0 + 8 <= Lout) {
        uint4 u;
        u.x = pack2bf(v[0], v[1]); u.y = pack2bf(v[2], v[3]);
        u.z = pack2bf(v[4], v[5]); u.w = pack2bf(v[6], v[7]);
        *(uint4*)(dst + t0) = u;
    } else {
#pragma unroll
        for (int j = 0; j < 8; ++j)
            if (t0 + j < Lout) dst[t0 + j] = f2bf(v[j]);
    }
}

__device__ __forceinline__ void dwt_lds_v2(const float* __restrict__ in, int Sin,
                                           float* __restrict__ aout,
                                           ushort* __restrict__ dout_g, int Lout, int tid) {
    const int NT = (Lout + 7) >> 3;
    for (int g = tid; g < NT; g += 256) {
        float xb[32];
        const int base = 16 * g - 16;
        if (base >= 0 && base + 32 <= Sin) {
#pragma unroll
            for (int q = 0; q < 8; ++q)
                *(float4*)(xb + 4 * q) = *(const float4*)(in + base + 4 * q);
        } else {
#pragma unroll
            for (int loc = 0; loc < 32; ++loc) {
                int i = base + loc;
                i = (i < 0) ? (-1 - i) : i;
                i = (i >= Sin) ? (2 * Sin - 1 - i) : i;
                xb[loc] = in[i];
            }
        }
        float lo[8], hi[8];
        dwt8_core(xb, lo, hi);
        const int t0 = 8 * g;
        if (t0 + 8 <= Lout) {
            *(float4*)(aout + t0)     = make_float4(lo[0], lo[1], lo[2], lo[3]);
            *(float4*)(aout + t0 + 4) = make_float4(lo[4], lo[5], lo[6], lo[7]);
        } else {
#pragma unroll
            for (int j = 0; j < 8; ++j) if (t0 + j < Lout) aout[t0 + j] = lo[j];
        }
        store_bf8(dout_g, t0, Lout, hi);
    }
}

__global__ __launch_bounds__(256) void dwt_full_kernel(const float* __restrict__ A,
                                                       const float2* __restrict__ stats,
                                                       ushort* __restrict__ d1,
                                                       ushort* __restrict__ d2,
                                                       ushort* __restrict__ d3,
                                                       ushort* __restrict__ d4,
                                                       ushort* __restrict__ a4) {
    __shared__ float bufA[4104];
    __shared__ float bufB[2064];
    const int row = blockIdx.x;
    const int tid = threadIdx.x;
    const float2 st = stats[row];
    const float* x = A + (size_t)row * S_LEN;
    ushort* d1r = d1 + (size_t)row * LB1;

    for (int g = tid; g < 513; g += 256) {
        const int base = 16 * g - 16;
        float xb[32];
        if (base >= 0 && base + 32 <= S_LEN) {
#pragma unroll
            for (int q = 0; q < 8; ++q) {
                float4 v = *(const float4*)(x + base + 4 * q);
                v.x = (v.x - st.x) * st.y; v.y = (v.y - st.x) * st.y;
                v.z = (v.z - st.x) * st.y; v.w = (v.w - st.x) * st.y;
                *(float4*)(xb + 4 * q) = v;
            }
        } else {
#pragma unroll
            for (int loc = 0; loc < 32; ++loc) {
                int i = base + loc;
                i = (i < 0) ? (-1 - i) : i;
                i = (i >= S_LEN) ? (2 * S_LEN - 1 - i) : i;
                xb[loc] = (x[i] - st.x) * st.y;
            }
        }
        float lo[8], hi[8];
        dwt8_core(xb, lo, hi);
        const int t0 = 8 * g;
#pragma unroll
        for (int j = 0; j < 8; ++j)
            if (t0 + j < L1v) bufA[t0 + j] = lo[j];
        store_bf8(d1r, t0, L1v, hi);
    }
    __syncthreads();
    dwt_lds_v2(bufA, L1v, bufB, d2 + (size_t)row * LB2, L2v, tid);
    __syncthreads();
    dwt_lds_v2(bufB, L2v, bufA, d3 + (size_t)row * LB3, L3v, tid);
    __syncthreads();
    dwt_lds_v2(bufA, L3v, bufB, d4 + (size_t)row * LB4, L4v, tid);
    __syncthreads();
    ushort* a4r = a4 + (size_t)row * LB4;
    for (int g = tid; g < 66; g += 256) {
        const int t0 = 8 * g;
        float v[8];
#pragma unroll
        for (int j = 0; j < 8; ++j)
            v[j] = (t0 + j < L4v) ? bufB[t0 + j] : 0.f;
        store_bf8(a4r, t0, 528, v);
    }
}

// ---------------- IDWT ----------------
__device__ __forceinline__ void idwt8_regs(const float* __restrict__ a,
                                           const float* __restrict__ d,
                                           int g, int Lc, float* __restrict__ y) {
    float av[12], dv[12];
    const int m0 = 4 * g;
    if (m0 + 12 <= Lc) {
#pragma unroll
        for (int q = 0; q < 3; ++q) {
            *(float4*)(av + 4 * q) = *(const float4*)(a + m0 + 4 * q);
            *(float4*)(dv + 4 * q) = *(const float4*)(d + m0 + 4 * q);
        }
    } else {
#pragma unroll
        for (int jj = 0; jj < 12; ++jj) {
            int m = m0 + jj;
            bool ok = (m < Lc);
            av[jj] = ok ? a[m] : 0.f;
            dv[jj] = ok ? d[m] : 0.f;
        }
    }
#pragma unroll
    for (int e = 0; e < 4; ++e) {
        float ye = 0.f, yo = 0.f;
#pragma unroll
        for (int j = 0; j < 8; ++j) {
            ye = fmaf(av[e + j], c_dlo[2 * j + 1], ye);
            ye = fmaf(dv[e + j], c_dlo[14 - 2 * j], ye);
            yo = fmaf(av[e + j], c_dlo[2 * j], yo);
            yo = fmaf(dv[e + j], -c_dlo[15 - 2 * j], yo);
        }
        y[2 * e] = ye;
        y[2 * e + 1] = yo;
    }
}

__device__ __forceinline__ void idwt_lds_v2(const float* __restrict__ a,
                                            const float* __restrict__ d,
                                            int Lc, int Lout, float* __restrict__ out, int tid) {
    const int NT = (Lout + 7) >> 3;
    for (int g = tid; g < NT; g += 256) {
        float y[8];
        idwt8_regs(a, d, g, Lc, y);
        const int t0 = 8 * g;
        if (t0 + 8 <= Lout) {
            *(float4*)(out + t0)     = make_float4(y[0], y[1], y[2], y[3]);
            *(float4*)(out + t0 + 4) = make_float4(y[4], y[5], y[6], y[7]);
        } else {
#pragma unroll
            for (int j = 0; j < 8; ++j) if (t0 + j < Lout) out[t0 + j] = y[j];
        }
    }
}

// load bf16 row -> f32 LDS (zero-fill beyond Lv)
__device__ __forceinline__ void gload_lds_bf(const ushort* __restrict__ src, int Lv,
                                             float* __restrict__ dst, int tid) {
    const int NG = (Lv + 7) >> 3;
    for (int g = tid; g < NG; g += 256) {
        uint4 u = *(const uint4*)(src + 8 * g);     // row pitch is 8-aligned; may read pad
        float v[8];
        v[0] = bfu((ushort)u.x); v[1] = bfu((ushort)(u.x >> 16));
        v[2] = bfu((ushort)u.y); v[3] = bfu((ushort)(u.y >> 16));
        v[4] = bfu((ushort)u.z); v[5] = bfu((ushort)(u.z >> 16));
        v[6] = bfu((ushort)u.w); v[7] = bfu((ushort)(u.w >> 16));
        const int t0 = 8 * g;
#pragma unroll
        for (int j = 0; j < 8; ++j)
            dst[t0 + j] = (t0 + j < Lv) ? v[j] : 0.f;
    }
}

__global__ __launch_bounds__(256) void idwt_full_kernel(const ushort* __restrict__ a4,
                                                        const ushort* __restrict__ d4,
                                                        const ushort* __restrict__ d3,
                                                        const ushort* __restrict__ d2,
                                                        const ushort* __restrict__ d1,
                                                        float* __restrict__ h,
                                                        const ushort* __restrict__ xs,
                                                        float2* __restrict__ statsOut) {
    __shared__ float bufY[4104];
    __shared__ float bufA[4104];
    __shared__ float bufD[4104];
    const int row = blockIdx.x;
    const int tid = threadIdx.x;

    gload_lds_bf(a4 + (size_t)row * LB4, L4v, bufA, tid);
    gload_lds_bf(d4 + (size_t)row * LB4, L4v, bufD, tid);
    __syncthreads();
    idwt_lds_v2(bufA, bufD, L4v, 1038, bufY, tid);
    __syncthreads();
    gload_lds_bf(d3 + (size_t)row * LB3, L3v, bufD, tid);
    __syncthreads();
    idwt_lds_v2(bufY, bufD, L3v, 2060, bufA, tid);
    __syncthreads();
    gload_lds_bf(d2 + (size_t)row * LB2, L2v, bufD, tid);
    __syncthreads();
    idwt_lds_v2(bufA, bufD, L2v, 4104, bufY, tid);
    __syncthreads();
    gload_lds_bf(d1 + (size_t)row * LB1, L1v, bufD, tid);
    __syncthreads();

    float* hrow = h + (size_t)row * S_LEN;
    const ushort* srow = xs + (size_t)row * S_LEN;
    float s = 0.f, ss = 0.f;
#pragma unroll
    for (int it = 0; it < 4; ++it) {
        const int g = it * 256 + tid;
        float y[8];
        idwt8_regs(bufY, bufD, g, L1v, y);
        const int t0 = 8 * g;
#pragma unroll
        for (int q = 0; q < 2; ++q) {
            uint2 sp = *(const uint2*)(srow + t0 + 4 * q);
            float4 hv = *(const float4*)(hrow + t0 + 4 * q);
            hv.x += gelu1(y[4 * q + 0] + bfu((ushort)sp.x));
            hv.y += gelu1(y[4 * q + 1] + bfu((ushort)(sp.x >> 16)));
            hv.z += gelu1(y[4 * q + 2] + bfu((ushort)sp.y));
            hv.w += gelu1(y[4 * q + 3] + bfu((ushort)(sp.y >> 16)));
            *(float4*)(hrow + t0 + 4 * q) = hv;
            s += hv.x + hv.y + hv.z + hv.w;
            ss = fmaf(hv.x, hv.x, fmaf(hv.y, hv.y, fmaf(hv.z, hv.z, fmaf(hv.w, hv.w, ss))));
        }
    }
    for (int off = 32; off > 0; off >>= 1) {
        s  += __shfl_down(s, off, 64);
        ss += __shfl_down(ss, off, 64);
    }
    __syncthreads();
    int lane = tid & 63, wv = tid >> 6;
    if (lane == 0) { bufA[wv] = s; bufA[4 + wv] = ss; }
    __syncthreads();
    if (tid == 0) {
        float tot  = bufA[0] + bufA[1] + bufA[2] + bufA[3];
        float tot2 = bufA[4] + bufA[5] + bufA[6] + bufA[7];
        float mean = tot * (1.0f / S_LEN);
        float var  = tot2 * (1.0f / S_LEN) - mean * mean;
        statsOut[row] = make_float2(mean, rsqrtf(var + 1e-5f));
    }
}

extern "C" void kernel_launch(void* const* d_in, const int* in_sizes, int n_in,
                              void* d_out, int out_size, void* d_ws, size_t ws_size,
                              hipStream_t stream) {
    const float* x       = (const float*)d_in[0];
    const float* lift_w  = (const float*)d_in[1];
    const float* lift_b  = (const float*)d_in[2];
    const float* blk_w_w = (const float*)d_in[3];
    const float* blk_w_b = (const float*)d_in[4];
    const float* blk_ca_w= (const float*)d_in[5];
    const float* blk_ca_b= (const float*)d_in[6];
    const float* blk_cd_w= (const float*)d_in[7];
    const float* blk_cd_b= (const float*)d_in[8];
    const float* blk_m1_w= (const float*)d_in[9];
    const float* blk_m1_b= (const float*)d_in[10];
    const float* blk_m2_w= (const float*)d_in[11];
    const float* blk_m2_b= (const float*)d_in[12];
    const float* p1_w    = (const float*)d_in[13];
    const float* p1_b    = (const float*)d_in[14];
    const float* p2_w    = (const float*)d_in[15];
    const float* p2_b    = (const float*)d_in[16];

    float* ws = (float*)d_ws;
    const size_t T32 = (size_t)NBC * S_LEN;
    float* A  = ws;                                  // residual stream (f32)
    ushort* Cc = (ushort*)(ws + T32);                // xs (bf16)
    ushort* d1 = Cc + T32;
    ushort* d2 = d1 + (size_t)NBC * LB1;
    ushort* d3 = d2 + (size_t)NBC * LB2;
    ushort* d4 = d3 + (size_t)NBC * LB3;
    ushort* a4 = d4 + (size_t)NBC * LB4;
    float2* statsBuf = (float2*)(a4 + (size_t)NBC * LB4 + 8);
    ushort* wbuf = (ushort*)(statsBuf + NBC);

    dim3 blk(256);

    prep_kernel<<<(WTOT + 255) / 256, blk, 0, stream>>>(blk_w_w, blk_m1_w, blk_m2_w,
                                                        blk_cd_w, blk_ca_w, p1_w, p2_w, wbuf);
    lift_kernel<<<(NBC * S_LEN) / 256, blk, 0, stream>>>(x, lift_w, lift_b, A);

    for (int i = 0; i < 4; ++i) {
        const float* w_b  = blk_w_b  + (size_t)i * 64;
        const float* ca_b = blk_ca_b + (size_t)i * 64;
        const float* cd_b = blk_cd_b + (size_t)i * 4 * 64;
        const float* m1_b = blk_m1_b + (size_t)i * 128;
        const float* m2_b = blk_m2_b + (size_t)i * 64;
        const ushort* convbf = wbuf + OFF_CONV + (size_t)i * 12288;
        const ushort* m1bf   = wbuf + OFF_M1   + (size_t)i * 8192;
        const ushort* m2bf   = wbuf + OFF_M2   + (size_t)i * 8192;
        const ushort* cdbf   = wbuf + OFF_CD   + (size_t)i * 16384;
        const ushort* cabf   = wbuf + OFF_CA   + (size_t)i * 4096;

        stats_kernel<<<NBC, blk, 0, stream>>>(A, statsBuf);
        conv3_mfma_kernel<<<dim3(S_LEN / 128, B_N), blk, 0, stream>>>(A, Cc, convbf, w_b, statsBuf);
        dwt_full_kernel<<<NBC, blk, 0, stream>>>(A, statsBuf, d1, d2, d3, d4, a4);

        wmix_kernel<<<dim3(69, B_N), blk, 0, stream>>>(d1, d2, d3, d4, a4,
                                                       cdbf, cd_b, cabf, ca_b);

        idwt_full_kernel<<<NBC, blk, 0, stream>>>(a4, d4, d3, d2, d1, A, Cc, statsBuf);
        mlp_kernel<<<dim3(S_LEN / 64, B_N), blk, 0, stream>>>(A, statsBuf, m1bf, m1_b, m2bf, m2_b);
    }

    head_kernel<<<dim3(S_LEN / 64, B_N), blk, 0, stream>>>(A, (float*)d_out,
                                                           wbuf + OFF_P1, p1_b,
                                                           wbuf + OFF_P2, p2_b);
}